// Round 1
// baseline (78.791 us; speedup 1.0000x reference)
//
#include <hip/hip_runtime.h>
#include <math.h>

// BoundsChecker: nearest-point-on-closed-path + Newton refine + frame/width
// outputs. SINGLE-DISPATCH version: bc_pack eliminated; bc_fused reads the
// raw inputs directly.
//
// Ledger (rounds 1-7): totals 131/89.5/80.4/70.4/70.9/70.8/69.1.
// total = kernel + ~65.5 us harness floor (256 MB d_ws poison = 40 us at
// 84% HBM peak + restores/small fills/graph gaps). rocprof r7: top-5
// dispatches are ALL poison fills; controllable budget ~3.6 us across two
// dispatches. r8 change: delete bc_pack.
//  - fine scan: window base shifted jc-31 -> jc-32 (even) so direct
//    *(float4*)(ref2+ia) loads are 16B-aligned -> same load count as the
//    old pairs[] table, no table build. Window +-32 covers the proven +-17.
//  - coarse scan: direct strided float2 loads (16 dwordx2 vs 8 dwordx4;
//    all L2-hits on 64KB input, TLP-hidden).
//  - Newton/final: two float2 loads on L1-hot lines; widths as 4 scalar
//    loads on lane 0 only.
// Saves one kernel execution + one graph dispatch gap (~1.5-2 us) for
// ~+0.3 us of extra latency-hidden loads. d_ws is now unused (poison fill
// is harness-fixed regardless).
//
// Inputs: positions[B,2] f32, refline_points[N,2] f32, left_widths[N] f32,
//         right_widths[N] f32, newton_iterations (int scalar in device mem).
// Output (flat concat, f32): r[B], point[B,2], tang[B,2], norm[B,2],
//         deltas[B,2], normal_projections[B], left[B], right[B] (12*B total).

#define DR_SAMP 1.0f
#define MAX_STEP 1.0f
#define TERM_EPS 1e-4f
#define TERM_DELTA_EPS 1e-2f

#define COARSE 32      // coarse stride (samples)
#define WIN 64         // fine window width (coarse best provably within +-17)
#define BLK 256
#define LPQ 16         // lanes per query -> B*16 threads, 2048 blocks

// Packed argmin key: top 19 bits of float(d2) | 13-bit index (N <= 8192).
// d2 >= 0 so float bits order as unsigned. Near-tie mis-ordering is absorbed
// by Newton (passed rounds 1-7 with absmax 0.031).
#define IDXBITS 13
#define IDXMASK ((1u << IDXBITS) - 1u)
#define KEYMASK (~IDXMASK)

__device__ __forceinline__ unsigned int pack_key(float d2, int i) {
    return (__float_as_uint(d2) & KEYMASK) | (unsigned int)i;
}

__device__ __forceinline__ int wrapN(int i, int N) {
    return (i < 0) ? i + N : ((i >= N) ? i - N : i);
}

// butterfly min over each aligned 16-lane group (xor 1,2,4,8 stays in-group)
__device__ __forceinline__ unsigned int grp16_min(unsigned int k) {
    k = min(k, (unsigned int)__shfl_xor((int)k, 1));
    k = min(k, (unsigned int)__shfl_xor((int)k, 2));
    k = min(k, (unsigned int)__shfl_xor((int)k, 4));
    k = min(k, (unsigned int)__shfl_xor((int)k, 8));
    return k;
}

__global__ __launch_bounds__(BLK, 8) void bc_fused(
    const float* __restrict__ pos, const float* __restrict__ ref,
    const float* __restrict__ lw, const float* __restrict__ rw,
    const int* __restrict__ nit_p, float* __restrict__ out, int B, int N)
{
    int gtid = blockIdx.x * BLK + threadIdx.x;
    int q = gtid / LPQ;               // 16 consecutive lanes share a query
    int l = threadIdx.x & (LPQ - 1);  // lane-in-group
    if (q >= B) return;

    int niter = nit_p[0];             // scalar load, issued early

    const float2* __restrict__ ref2 = (const float2*)ref;
    const float L = (float)N * DR_SAMP;
    float px = pos[2 * q], py = pos[2 * q + 1];  // group-broadcast loads

    // ---- coarse scan: 16 cands/lane via 16 direct float2 loads ------------
    // 256 candidate points spread over the 64KB ref array: L2-resident
    // (inputs restored by the harness each iter), latency hidden by TLP.
    int NC = N / COARSE;  // 256 for N=8192; NC % (2*LPQ) == 0
    unsigned int c0 = 0xFFFFFFFFu, c1 = 0xFFFFFFFFu;
    for (int j = l; j < NC; j += 2 * LPQ) {
        int ja = j * COARSE, jb = (j + LPQ) * COARSE;
        float2 a = ref2[ja];
        float2 b = ref2[jb];
        float dxa = px - a.x, dya = py - a.y;
        float dxb = px - b.x, dyb = py - b.y;
        c0 = min(c0, pack_key(fmaf(dxa, dxa, dya * dya), ja));
        c1 = min(c1, pack_key(fmaf(dxb, dxb, dyb * dyb), jb));
    }
    int jc = (int)(grp16_min(min(c0, c1)) & IDXMASK);

    // ---- fine exact scan: 64-wide window, 4 cands/lane via 2 float4 loads -
    // base = jc - 32 is EVEN (jc is a COARSE multiple, N even), so every
    // ia = base + 2l + 32t is even after wrap -> (ref2 + ia) is 16B-aligned
    // and one float4 load yields (ref[ia], ref[ia+1]) directly.
    unsigned int fbest = 0xFFFFFFFFu;
    int base = jc - WIN / 2;
#pragma unroll
    for (int t = 0; t < 2; ++t) {
        int ia = wrapN(base + 2 * l + t * 2 * LPQ, N);
        float4 pr = *(const float4*)(ref2 + ia);
        float dxa = px - pr.x, dya = py - pr.y;
        float dxb = px - pr.z, dyb = py - pr.w;
        fbest = min(fbest, pack_key(fmaf(dxa, dxa, dya * dya), ia));
        fbest = min(fbest, pack_key(fmaf(dxb, dxb, dyb * dyb), ia + 1));
    }
    fbest = grp16_min(fbest);
    float r = (float)(int)(fbest & IDXMASK) * DR_SAMP;

    // ---- Newton refinement: replicated across the 16 group lanes ----------
    // Loads hit L1 (fine scan just touched this window). EARLY EXIT when all
    // 64 lanes are done -- exact: done is monotone and post-done iterations
    // are masked no-ops in the reference.
    bool done = false;
    for (int it = 0; it < niter; ++it) {
        float fu = floorf(r);
        int i0 = (int)fu;
        if (i0 >= N) i0 -= N;
        int i1 = (i0 + 1 == N) ? 0 : i0 + 1;
        float frac = r - fu;
        float2 p0 = ref2[i0], p1 = ref2[i1];
        float ex = p1.x - p0.x, ey = p1.y - p0.y;
        float ptx = fmaf(frac, ex, p0.x);
        float pty = fmaf(frac, ey, p0.y);
        float inv = rsqrtf(fmaf(ex, ex, ey * ey));
        float tx = ex * inv, ty = ey * inv;
        float dx = px - ptx, dy = py - pty;
        float fprime = -(dx * tx + dy * ty);
        float step = fminf(fmaxf(-fprime, -MAX_STEP), MAX_STEP);
        if (!done) {
            r += step;  // step in [-1,1] => r stays in (-1, L+1)
            if (r >= L) r -= L;
            if (r < 0.0f) r += L;
        }
        done = done || (fabsf(fprime) < TERM_EPS) || (fabsf(step) < TERM_DELTA_EPS);
        if (__all(done)) break;   // wave-uniform exit, typically after 1-2 iters
    }

    // ---- final eval + outputs (lane 0 of each 16-lane group stores;
    //      active lanes' addresses are consecutive -> coalesced) ------------
    if (l != 0) return;

    float fu = floorf(r);
    int i0 = (int)fu;
    if (i0 >= N) i0 -= N;
    int i1 = (i0 + 1 == N) ? 0 : i0 + 1;
    float frac = r - fu;
    float2 p0 = ref2[i0], p1 = ref2[i1];
    float ex = p1.x - p0.x, ey = p1.y - p0.y;
    float ptx = fmaf(frac, ex, p0.x);
    float pty = fmaf(frac, ey, p0.y);
    float inv = rsqrtf(fmaf(ex, ex, ey * ey));
    float tx = ex * inv;
    float ty = ey * inv;
    float nx = -ty, ny = tx;
    float dx = px - ptx, dy = py - pty;
    float proj = dx * nx + dy * ny;
    float lv = lw[i0] * (1.0f - frac) + lw[i1] * frac;
    float rv = rw[i0] * (1.0f - frac) + rw[i1] * frac;

    out[q] = r;
    *(float2*)(out + B + 2 * q)     = make_float2(ptx, pty);
    *(float2*)(out + 3 * B + 2 * q) = make_float2(tx, ty);
    *(float2*)(out + 5 * B + 2 * q) = make_float2(nx, ny);
    *(float2*)(out + 7 * B + 2 * q) = make_float2(dx, dy);
    out[9 * B + q]  = proj;
    out[10 * B + q] = lv;
    out[11 * B + q] = rv;
}

extern "C" void kernel_launch(void* const* d_in, const int* in_sizes, int n_in,
                              void* d_out, int out_size, void* d_ws, size_t ws_size,
                              hipStream_t stream) {
    const float* pos = (const float*)d_in[0];
    const float* ref = (const float*)d_in[1];
    const float* lw  = (const float*)d_in[2];
    const float* rw  = (const float*)d_in[3];
    const int*   nit = (const int*)d_in[4];
    int B = in_sizes[0] / 2;
    int N = in_sizes[1] / 2;
    float* out = (float*)d_out;
    (void)d_ws; (void)ws_size;  // unused: single-dispatch, no LUT build

    // 16 lanes/query, BLK=256 -> 2048 blocks = 8 blocks/CU = 32 waves/CU.
    long long threads = (long long)B * LPQ;
    int nb = (int)((threads + BLK - 1) / BLK);
    bc_fused<<<nb, BLK, 0, stream>>>(pos, ref, lw, rw, nit, out, B, N);
}

// Round 2
// 69.174 us; speedup vs baseline: 1.1390x; 1.1390x over previous
//
#include <hip/hip_runtime.h>
#include <math.h>

// BoundsChecker: nearest-point-on-closed-path + Newton refine + frame/width
// outputs. Two dispatches: MINIMAL pack (2 KB coarse4 table only) + fused main.
//
// Ledger: r1-7 totals 131/89.5/80.4/70.4/70.9/70.8/69.1; r8 (single-dispatch,
// direct strided coarse) REGRESSED to 78.8. Post-mortem: the 256 coarse
// candidates live at 256 B stride in ref -> each coarse load touches 16
// distinct lines (8 B useful each) and the ~16-32 KB coarse footprint
// thrashes the 32 KB L1 every pass, which also knocks the fine-window lines
// out from under the Newton dependent-load chain. The 2 KB packed coarse4
// table was what kept L1 clean -- its value was footprint, not load count.
//
// r9: restore a MINIMAL pack: only coarse4 (128 float4 = 2 KB; 128 threads,
// 2 scattered loads + 1 store each -- 128x less write traffic than the r7
// pack which also built pairs/wpair). Keep r8's genuinely-good parts:
//  - fine scan: window base jc-32 (even) -> direct 16B-aligned float4 loads
//    of (ref[ia], ref[ia+1]); fully coalesced, no pairs[] table.
//  - Newton/final: direct float2 loads on L1-hot lines; widths as 4 scalar
//    lane-0 loads. No wpair table.
//
// Inputs: positions[B,2] f32, refline_points[N,2] f32, left_widths[N] f32,
//         right_widths[N] f32, newton_iterations (int scalar in device mem).
// Output (flat concat, f32): r[B], point[B,2], tang[B,2], norm[B,2],
//         deltas[B,2], normal_projections[B], left[B], right[B] (12*B total).

#define DR_SAMP 1.0f
#define MAX_STEP 1.0f
#define TERM_EPS 1e-4f
#define TERM_DELTA_EPS 1e-2f

#define COARSE 32      // coarse stride (samples)
#define WIN 64         // fine window width (coarse best provably within +-17)
#define BLK 256
#define LPQ 16         // lanes per query -> B*16 threads, 2048 blocks

// Packed argmin key: top 19 bits of float(d2) | 13-bit index (N <= 8192).
// d2 >= 0 so float bits order as unsigned. Near-tie mis-ordering is absorbed
// by Newton (passed rounds 1-8 with absmax 0.031).
#define IDXBITS 13
#define IDXMASK ((1u << IDXBITS) - 1u)
#define KEYMASK (~IDXMASK)

__device__ __forceinline__ unsigned int pack_key(float d2, int i) {
    return (__float_as_uint(d2) & KEYMASK) | (unsigned int)i;
}

__device__ __forceinline__ int wrapN(int i, int N) {
    return (i < 0) ? i + N : ((i >= N) ? i - N : i);
}

// butterfly min over each aligned 16-lane group (xor 1,2,4,8 stays in-group)
__device__ __forceinline__ unsigned int grp16_min(unsigned int k) {
    k = min(k, (unsigned int)__shfl_xor((int)k, 1));
    k = min(k, (unsigned int)__shfl_xor((int)k, 2));
    k = min(k, (unsigned int)__shfl_xor((int)k, 4));
    k = min(k, (unsigned int)__shfl_xor((int)k, 8));
    return k;
}

// ---- minimal pack: coarse4[j] = (ref[2j*COARSE], ref[(2j+1)*COARSE]) ----
// NC2 = N/(2*COARSE) = 128 entries = 2 KB. 2 scattered loads + 1 store per
// thread; 2 blocks x 64 threads so the cold HBM line fetches overlap.
__global__ __launch_bounds__(64) void bc_pack(
    const float* __restrict__ ref, float4* __restrict__ coarse4, int N)
{
    int t = blockIdx.x * 64 + threadIdx.x;
    int NC2 = N / (2 * COARSE);
    const float2* __restrict__ ref2 = (const float2*)ref;
    if (t < NC2) {
        float2 a = ref2[(2 * t) * COARSE];
        float2 b = ref2[(2 * t + 1) * COARSE];
        coarse4[t] = make_float4(a.x, a.y, b.x, b.y);
    }
}

__global__ __launch_bounds__(BLK, 8) void bc_fused(
    const float* __restrict__ pos, const float* __restrict__ ref,
    const float* __restrict__ lw, const float* __restrict__ rw,
    const float4* __restrict__ coarse4, const int* __restrict__ nit_p,
    float* __restrict__ out, int B, int N)
{
    int gtid = blockIdx.x * BLK + threadIdx.x;
    int q = gtid / LPQ;               // 16 consecutive lanes share a query
    int l = threadIdx.x & (LPQ - 1);  // lane-in-group
    if (q >= B) return;

    int niter = nit_p[0];             // scalar load, issued early

    const float2* __restrict__ ref2 = (const float2*)ref;
    const float L = (float)N * DR_SAMP;
    float px = pos[2 * q], py = pos[2 * q + 1];  // group-broadcast loads

    // ---- coarse scan: 16 cands/lane via 8 float4 loads from the 2 KB
    //      L1-resident packed table (footprint is the point -- see header) --
    int NCP = N / (2 * COARSE);  // 128 packed pairs for N=8192
    unsigned int c0 = 0xFFFFFFFFu, c1 = 0xFFFFFFFFu;
    for (int j = l; j < NCP; j += 2 * LPQ) {
        float4 pa = coarse4[j];
        float4 pb = coarse4[j + LPQ];
        int ma = 2 * j * COARSE, mb = 2 * (j + LPQ) * COARSE;
        float dxa = px - pa.x, dya = py - pa.y;
        float dxb = px - pa.z, dyb = py - pa.w;
        c0 = min(c0, pack_key(fmaf(dxa, dxa, dya * dya), ma));
        c1 = min(c1, pack_key(fmaf(dxb, dxb, dyb * dyb), ma + COARSE));
        float dxc = px - pb.x, dyc = py - pb.y;
        float dxd = px - pb.z, dyd = py - pb.w;
        c0 = min(c0, pack_key(fmaf(dxc, dxc, dyc * dyc), mb));
        c1 = min(c1, pack_key(fmaf(dxd, dxd, dyd * dyd), mb + COARSE));
    }
    int jc = (int)(grp16_min(min(c0, c1)) & IDXMASK);

    // ---- fine exact scan: 64-wide window, 4 cands/lane via 2 float4 loads -
    // base = jc - 32 is EVEN (jc is a COARSE multiple, N even), so every
    // ia = base + 2l + 32t is even after wrap -> (ref2 + ia) is 16B-aligned
    // and one float4 load yields (ref[ia], ref[ia+1]) directly.
    unsigned int fbest = 0xFFFFFFFFu;
    int base = jc - WIN / 2;
#pragma unroll
    for (int t = 0; t < 2; ++t) {
        int ia = wrapN(base + 2 * l + t * 2 * LPQ, N);
        float4 pr = *(const float4*)(ref2 + ia);
        float dxa = px - pr.x, dya = py - pr.y;
        float dxb = px - pr.z, dyb = py - pr.w;
        fbest = min(fbest, pack_key(fmaf(dxa, dxa, dya * dya), ia));
        fbest = min(fbest, pack_key(fmaf(dxb, dxb, dyb * dyb), ia + 1));
    }
    fbest = grp16_min(fbest);
    float r = (float)(int)(fbest & IDXMASK) * DR_SAMP;

    // ---- Newton refinement: replicated across the 16 group lanes ----------
    // Loads hit L1 (fine scan just touched this window). EARLY EXIT when all
    // 64 lanes are done -- exact: done is monotone and post-done iterations
    // are masked no-ops in the reference.
    bool done = false;
    for (int it = 0; it < niter; ++it) {
        float fu = floorf(r);
        int i0 = (int)fu;
        if (i0 >= N) i0 -= N;
        int i1 = (i0 + 1 == N) ? 0 : i0 + 1;
        float frac = r - fu;
        float2 p0 = ref2[i0], p1 = ref2[i1];
        float ex = p1.x - p0.x, ey = p1.y - p0.y;
        float ptx = fmaf(frac, ex, p0.x);
        float pty = fmaf(frac, ey, p0.y);
        float inv = rsqrtf(fmaf(ex, ex, ey * ey));
        float tx = ex * inv, ty = ey * inv;
        float dx = px - ptx, dy = py - pty;
        float fprime = -(dx * tx + dy * ty);
        float step = fminf(fmaxf(-fprime, -MAX_STEP), MAX_STEP);
        if (!done) {
            r += step;  // step in [-1,1] => r stays in (-1, L+1)
            if (r >= L) r -= L;
            if (r < 0.0f) r += L;
        }
        done = done || (fabsf(fprime) < TERM_EPS) || (fabsf(step) < TERM_DELTA_EPS);
        if (__all(done)) break;   // wave-uniform exit, typically after 1-2 iters
    }

    // ---- final eval + outputs (lane 0 of each 16-lane group stores;
    //      active lanes' addresses are consecutive -> coalesced) ------------
    if (l != 0) return;

    float fu = floorf(r);
    int i0 = (int)fu;
    if (i0 >= N) i0 -= N;
    int i1 = (i0 + 1 == N) ? 0 : i0 + 1;
    float frac = r - fu;
    float2 p0 = ref2[i0], p1 = ref2[i1];
    float ex = p1.x - p0.x, ey = p1.y - p0.y;
    float ptx = fmaf(frac, ex, p0.x);
    float pty = fmaf(frac, ey, p0.y);
    float inv = rsqrtf(fmaf(ex, ex, ey * ey));
    float tx = ex * inv;
    float ty = ey * inv;
    float nx = -ty, ny = tx;
    float dx = px - ptx, dy = py - pty;
    float proj = dx * nx + dy * ny;
    float lv = lw[i0] * (1.0f - frac) + lw[i1] * frac;
    float rv = rw[i0] * (1.0f - frac) + rw[i1] * frac;

    out[q] = r;
    *(float2*)(out + B + 2 * q)     = make_float2(ptx, pty);
    *(float2*)(out + 3 * B + 2 * q) = make_float2(tx, ty);
    *(float2*)(out + 5 * B + 2 * q) = make_float2(nx, ny);
    *(float2*)(out + 7 * B + 2 * q) = make_float2(dx, dy);
    out[9 * B + q]  = proj;
    out[10 * B + q] = lv;
    out[11 * B + q] = rv;
}

extern "C" void kernel_launch(void* const* d_in, const int* in_sizes, int n_in,
                              void* d_out, int out_size, void* d_ws, size_t ws_size,
                              hipStream_t stream) {
    const float* pos = (const float*)d_in[0];
    const float* ref = (const float*)d_in[1];
    const float* lw  = (const float*)d_in[2];
    const float* rw  = (const float*)d_in[3];
    const int*   nit = (const int*)d_in[4];
    int B = in_sizes[0] / 2;
    int N = in_sizes[1] / 2;
    float* out = (float*)d_out;

    // d_ws (re-poisoned by harness each call -> rebuild each call):
    // coarse4[N/64] float4 = 2 KB. Nothing else staged.
    float4* coarse4 = (float4*)d_ws;

    int NC2 = N / (2 * COARSE);              // 128
    int nbp = (NC2 + 63) / 64;               // 2 blocks x 64 threads
    bc_pack<<<nbp, 64, 0, stream>>>(ref, coarse4, N);

    // 16 lanes/query, BLK=256 -> 2048 blocks = 8 blocks/CU = 32 waves/CU.
    long long threads = (long long)B * LPQ;
    int nb = (int)((threads + BLK - 1) / BLK);
    bc_fused<<<nb, BLK, 0, stream>>>(pos, ref, lw, rw, coarse4, nit, out, B, N);
}

// Round 3
// 67.578 us; speedup vs baseline: 1.1659x; 1.0236x over previous
//
#include <hip/hip_runtime.h>
#include <math.h>

// BoundsChecker: nearest-point-on-closed-path + Newton refine + frame/width
// outputs. SINGLE DISPATCH: coarse table staged in LDS per-block (no pack
// kernel, no graph edge).
//
// Ledger: r1-7 totals 131/89.5/80.4/70.4/70.9/70.8/69.1; r8 single-dispatch
// w/ direct strided coarse REGRESSED to 78.8 (each 16-lane group re-fetched
// all 256 coarse points at 256B stride: ~512 MB L2 traffic = ~15 us); r9
// minimal 2KB pack restored 69.17 (== r7 -> pack cost is dispatch+graph-gap
// ~1.5-2 us, not execution).
//
// r10: keep ONE dense shared copy of the coarse set, but in LDS instead of a
// packed global table: each block gathers the 256 coarse points once
// (256 threads x one float2; ~34 MB total L2 traffic = ~1 us), then all 16
// query groups scan the 2 KB LDS copy via ds_read_b128 (groups 1..3 mirror
// group 0's addresses -> LDS broadcast, no bank conflicts). Fine scan /
// Newton / outputs unchanged from r9 (direct aligned float4 fine loads,
// direct float2 Newton loads, lane-0 scalar width loads).
//
// Inputs: positions[B,2] f32, refline_points[N,2] f32, left_widths[N] f32,
//         right_widths[N] f32, newton_iterations (int scalar in device mem).
// Output (flat concat, f32): r[B], point[B,2], tang[B,2], norm[B,2],
//         deltas[B,2], normal_projections[B], left[B], right[B] (12*B total).

#define DR_SAMP 1.0f
#define MAX_STEP 1.0f
#define TERM_EPS 1e-4f
#define TERM_DELTA_EPS 1e-2f

#define COARSE 32      // coarse stride (samples)
#define WIN 64         // fine window width (coarse best provably within +-17)
#define BLK 256
#define LPQ 16         // lanes per query -> B*16 threads, 2048 blocks
#define NCMAX 256      // max coarse entries staged (N<=8192 -> N/COARSE<=256)

// Packed argmin key: top 19 bits of float(d2) | 13-bit index (N <= 8192).
// d2 >= 0 so float bits order as unsigned. Near-tie mis-ordering is absorbed
// by Newton (passed rounds 1-9 with absmax 0.031).
#define IDXBITS 13
#define IDXMASK ((1u << IDXBITS) - 1u)
#define KEYMASK (~IDXMASK)

__device__ __forceinline__ unsigned int pack_key(float d2, int i) {
    return (__float_as_uint(d2) & KEYMASK) | (unsigned int)i;
}

__device__ __forceinline__ int wrapN(int i, int N) {
    return (i < 0) ? i + N : ((i >= N) ? i - N : i);
}

// butterfly min over each aligned 16-lane group (xor 1,2,4,8 stays in-group)
__device__ __forceinline__ unsigned int grp16_min(unsigned int k) {
    k = min(k, (unsigned int)__shfl_xor((int)k, 1));
    k = min(k, (unsigned int)__shfl_xor((int)k, 2));
    k = min(k, (unsigned int)__shfl_xor((int)k, 4));
    k = min(k, (unsigned int)__shfl_xor((int)k, 8));
    return k;
}

__global__ __launch_bounds__(BLK, 8) void bc_fused(
    const float* __restrict__ pos, const float* __restrict__ ref,
    const float* __restrict__ lw, const float* __restrict__ rw,
    const int* __restrict__ nit_p, float* __restrict__ out, int B, int N)
{
    // LDS coarse table: float4 view for conflict-free b128 reads.
    __shared__ float4 c4[NCMAX / 2];          // 2 KB

    int tid = blockIdx.x * BLK + threadIdx.x;
    int q = tid / LPQ;                // 16 consecutive lanes share a query
    int l = threadIdx.x & (LPQ - 1);  // lane-in-group

    const float2* __restrict__ ref2 = (const float2*)ref;
    int NC = N / COARSE;              // 256 for N=8192

    // ---- stage coarse set: one scattered float2 per thread, once/block ----
    {
        float2* c2 = (float2*)c4;
        for (int j = threadIdx.x; j < NC; j += BLK)
            c2[j] = ref2[j * COARSE];
    }
    __syncthreads();
    if (q >= B) return;               // grid is exact; kept for safety

    int niter = nit_p[0];             // scalar load, issued early

    const float L = (float)N * DR_SAMP;
    float px = pos[2 * q], py = pos[2 * q + 1];  // group-broadcast loads

    // ---- coarse scan: 16 cands/lane via 8 LDS b128 reads ------------------
    int NCP = NC / 2;                 // 128 packed pairs
    unsigned int c0 = 0xFFFFFFFFu, c1 = 0xFFFFFFFFu;
    for (int j = l; j < NCP; j += 2 * LPQ) {
        float4 pa = c4[j];
        float4 pb = c4[j + LPQ];
        int ma = 2 * j * COARSE, mb = 2 * (j + LPQ) * COARSE;
        float dxa = px - pa.x, dya = py - pa.y;
        float dxb = px - pa.z, dyb = py - pa.w;
        c0 = min(c0, pack_key(fmaf(dxa, dxa, dya * dya), ma));
        c1 = min(c1, pack_key(fmaf(dxb, dxb, dyb * dyb), ma + COARSE));
        float dxc = px - pb.x, dyc = py - pb.y;
        float dxd = px - pb.z, dyd = py - pb.w;
        c0 = min(c0, pack_key(fmaf(dxc, dxc, dyc * dyc), mb));
        c1 = min(c1, pack_key(fmaf(dxd, dxd, dyd * dyd), mb + COARSE));
    }
    int jc = (int)(grp16_min(min(c0, c1)) & IDXMASK);

    // ---- fine exact scan: 64-wide window, 4 cands/lane via 2 float4 loads -
    // base = jc - 32 is EVEN (jc is a COARSE multiple, N even), so every
    // ia = base + 2l + 32t is even after wrap -> (ref2 + ia) is 16B-aligned
    // and one float4 load yields (ref[ia], ref[ia+1]) directly.
    unsigned int fbest = 0xFFFFFFFFu;
    int base = jc - WIN / 2;
#pragma unroll
    for (int t = 0; t < 2; ++t) {
        int ia = wrapN(base + 2 * l + t * 2 * LPQ, N);
        float4 pr = *(const float4*)(ref2 + ia);
        float dxa = px - pr.x, dya = py - pr.y;
        float dxb = px - pr.z, dyb = py - pr.w;
        fbest = min(fbest, pack_key(fmaf(dxa, dxa, dya * dya), ia));
        fbest = min(fbest, pack_key(fmaf(dxb, dxb, dyb * dyb), ia + 1));
    }
    fbest = grp16_min(fbest);
    float r = (float)(int)(fbest & IDXMASK) * DR_SAMP;

    // ---- Newton refinement: replicated across the 16 group lanes ----------
    // Loads hit L1 (fine scan just touched this window). EARLY EXIT when all
    // 64 lanes are done -- exact: done is monotone and post-done iterations
    // are masked no-ops in the reference.
    bool done = false;
    for (int it = 0; it < niter; ++it) {
        float fu = floorf(r);
        int i0 = (int)fu;
        if (i0 >= N) i0 -= N;
        int i1 = (i0 + 1 == N) ? 0 : i0 + 1;
        float frac = r - fu;
        float2 p0 = ref2[i0], p1 = ref2[i1];
        float ex = p1.x - p0.x, ey = p1.y - p0.y;
        float ptx = fmaf(frac, ex, p0.x);
        float pty = fmaf(frac, ey, p0.y);
        float inv = rsqrtf(fmaf(ex, ex, ey * ey));
        float tx = ex * inv, ty = ey * inv;
        float dx = px - ptx, dy = py - pty;
        float fprime = -(dx * tx + dy * ty);
        float step = fminf(fmaxf(-fprime, -MAX_STEP), MAX_STEP);
        if (!done) {
            r += step;  // step in [-1,1] => r stays in (-1, L+1)
            if (r >= L) r -= L;
            if (r < 0.0f) r += L;
        }
        done = done || (fabsf(fprime) < TERM_EPS) || (fabsf(step) < TERM_DELTA_EPS);
        if (__all(done)) break;   // wave-uniform exit, typically after 1-2 iters
    }

    // ---- final eval + outputs (lane 0 of each 16-lane group stores;
    //      active lanes' addresses are consecutive -> coalesced) ------------
    if (l != 0) return;

    float fu = floorf(r);
    int i0 = (int)fu;
    if (i0 >= N) i0 -= N;
    int i1 = (i0 + 1 == N) ? 0 : i0 + 1;
    float frac = r - fu;
    float2 p0 = ref2[i0], p1 = ref2[i1];
    float ex = p1.x - p0.x, ey = p1.y - p0.y;
    float ptx = fmaf(frac, ex, p0.x);
    float pty = fmaf(frac, ey, p0.y);
    float inv = rsqrtf(fmaf(ex, ex, ey * ey));
    float tx = ex * inv;
    float ty = ey * inv;
    float nx = -ty, ny = tx;
    float dx = px - ptx, dy = py - pty;
    float proj = dx * nx + dy * ny;
    float lv = lw[i0] * (1.0f - frac) + lw[i1] * frac;
    float rv = rw[i0] * (1.0f - frac) + rw[i1] * frac;

    out[q] = r;
    *(float2*)(out + B + 2 * q)     = make_float2(ptx, pty);
    *(float2*)(out + 3 * B + 2 * q) = make_float2(tx, ty);
    *(float2*)(out + 5 * B + 2 * q) = make_float2(nx, ny);
    *(float2*)(out + 7 * B + 2 * q) = make_float2(dx, dy);
    out[9 * B + q]  = proj;
    out[10 * B + q] = lv;
    out[11 * B + q] = rv;
}

extern "C" void kernel_launch(void* const* d_in, const int* in_sizes, int n_in,
                              void* d_out, int out_size, void* d_ws, size_t ws_size,
                              hipStream_t stream) {
    const float* pos = (const float*)d_in[0];
    const float* ref = (const float*)d_in[1];
    const float* lw  = (const float*)d_in[2];
    const float* rw  = (const float*)d_in[3];
    const int*   nit = (const int*)d_in[4];
    int B = in_sizes[0] / 2;
    int N = in_sizes[1] / 2;
    float* out = (float*)d_out;
    (void)d_ws; (void)ws_size;  // unused: coarse table lives in LDS

    // 16 lanes/query, BLK=256 -> 2048 blocks = 8 blocks/CU = 32 waves/CU.
    long long threads = (long long)B * LPQ;
    int nb = (int)((threads + BLK - 1) / BLK);
    bc_fused<<<nb, BLK, 0, stream>>>(pos, ref, lw, rw, nit, out, B, N);
}